// Round 3
// baseline (2573.318 us; speedup 1.0000x reference)
//
#include <hip/hip_runtime.h>

#define N_SITES  100000
#define N_BONDS  800000
#define N_GRAPHS 1000

// ---------- LDS staging helpers (fp32) ----------
template<int CNT>
__device__ __forceinline__ void stage_w(float* dst, const float* __restrict__ src, int tid, int nth){
  for (int i = tid; i < CNT; i += nth) dst[i] = src[i];
}
__device__ __forceinline__ void stage_b(float* dst, const float* __restrict__ src, int n, int tid){
  if (tid < n) dst[tid] = src[tid];
}

// acc[r] += sum_k x[r*XS + k] * W[k*N + j]
// W in LDS [K][N]: lane-consecutive reads (2-way bank alias = free).
// x in LDS, read as same-address float4 broadcasts (conflict-free).
template<int K, int N, int R, int XS>
__device__ __forceinline__ void layerR(const float* __restrict__ W,
                                       const float* __restrict__ x,
                                       float* __restrict__ acc, int j)
{
  #pragma unroll
  for (int k = 0; k < K; k += 4){
    float w0 = W[(k+0)*N + j];
    float w1 = W[(k+1)*N + j];
    float w2 = W[(k+2)*N + j];
    float w3 = W[(k+3)*N + j];
    #pragma unroll
    for (int r = 0; r < R; ++r){
      float4 xv = *(const float4*)(x + r*XS + k);
      acc[r] = fmaf(xv.x, w0, acc[r]);
      acc[r] = fmaf(xv.y, w1, acc[r]);
      acc[r] = fmaf(xv.z, w2, acc[r]);
      acc[r] = fmaf(xv.w, w3, acc[r]);
    }
  }
}

__device__ __forceinline__ int lbound(const int* __restrict__ a, int n, int v){
  int lo = 0, hi = n;
  while (lo < hi){ int m = (lo+hi) >> 1; if (a[m] < v) lo = m+1; else hi = m; }
  return lo;
}

// ---------- kernel 1: states path prep (1000 rows) ----------
__global__ __launch_bounds__(256) void prep_small_kernel(
    const float* __restrict__ states,
    const float* __restrict__ w1, const float* __restrict__ b1,
    const float* __restrict__ w2, const float* __restrict__ b2,
    const float* __restrict__ w_bu1, const float* __restrict__ b_bu1,
    const float* __restrict__ w_su1, const float* __restrict__ b_su1,
    const float* __restrict__ w_stu1, const float* __restrict__ b_stu1,
    float* __restrict__ states2, float* __restrict__ statec_bu,
    float* __restrict__ statec_su, float* __restrict__ statec_stu)
{
  __shared__ float W1[4096], W2[4096], WD[4096], WsuC[4096], WstuC[4096];
  __shared__ float B1[64], B2[64], Bbu[64], Bsu[64], Bstu[64];
  __shared__ alignas(16) float xs[4][64];
  __shared__ alignas(16) float hs[4][64];
  int tid = threadIdx.x;
  stage_w<4096>(W1,    w1,              tid, 256);
  stage_w<4096>(W2,    w2,              tid, 256);
  stage_w<4096>(WD,    w_bu1 + 192*64,  tid, 256);
  stage_w<4096>(WsuC,  w_su1 + 128*64,  tid, 256);
  stage_w<4096>(WstuC, w_stu1 + 128*64, tid, 256);
  stage_b(B1, b1, 64, tid);  stage_b(B2, b2, 64, tid);
  stage_b(Bbu, b_bu1, 64, tid); stage_b(Bsu, b_su1, 64, tid); stage_b(Bstu, b_stu1, 64, tid);
  __syncthreads();
  int w = tid >> 6, lane = tid & 63;
  int g = blockIdx.x*4 + w;                       // 250 blocks * 4 = exactly 1000
  xs[w][lane] = states[(size_t)g*64 + lane];
  __syncthreads();
  float a = B1[lane];
  layerR<64,64,1,64>(W1, xs[w], &a, lane);
  hs[w][lane] = fmaxf(a, 0.f);
  __syncthreads();
  a = B2[lane];
  layerR<64,64,1,64>(W2, hs[w], &a, lane);
  float s2 = fmaxf(a, 0.f);
  __syncthreads();
  xs[w][lane] = s2;
  __syncthreads();
  size_t o = (size_t)g*64 + lane;
  float abu = Bbu[lane], asu = Bsu[lane], astu = Bstu[lane];
  layerR<64,64,1,64>(WD,    xs[w], &abu,  lane);
  layerR<64,64,1,64>(WsuC,  xs[w], &asu,  lane);
  layerR<64,64,1,64>(WstuC, xs[w], &astu, lane);
  states2[o]    = s2;
  statec_bu[o]  = abu;
  statec_su[o]  = asu;
  statec_stu[o] = astu;
}

// ---------- kernel 2: sites pre-MLP (100000 rows) -> fp32 sites2 (aliased into d_out sites region) ----------
__global__ __launch_bounds__(256) void sites_pre_kernel(
    const float* __restrict__ sites,
    const float* __restrict__ w1, const float* __restrict__ b1,
    const float* __restrict__ w2, const float* __restrict__ b2,
    float* __restrict__ sites2)
{
  __shared__ float W1[4096], W2[4096];
  __shared__ float B1[64], B2[64];
  __shared__ alignas(16) float xs[4][4][64];
  __shared__ alignas(16) float hs[4][4][64];
  int tid = threadIdx.x;
  stage_w<4096>(W1, w1, tid, 256);
  stage_w<4096>(W2, w2, tid, 256);
  stage_b(B1, b1, 64, tid); stage_b(B2, b2, 64, tid);
  __syncthreads();
  int w = tid >> 6, lane = tid & 63;
  int wgid = blockIdx.x*4 + w;                     // 1024 blocks * 4 waves = 4096
  for (int n = 0; n < 7; ++n){                     // 7*4096 >= 25000 groups of 4 sites
    int G = n*4096 + wgid;
    bool v = G < 25000;
    if (v){
      #pragma unroll
      for (int r = 0; r < 4; ++r)
        xs[w][r][lane] = sites[((size_t)(4*G + r))*64 + lane];
    }
    __syncthreads();
    if (v){
      float a[4] = {B1[lane], B1[lane], B1[lane], B1[lane]};
      layerR<64,64,4,64>(W1, &xs[w][0][0], a, lane);
      #pragma unroll
      for (int r = 0; r < 4; ++r) hs[w][r][lane] = fmaxf(a[r], 0.f);
    }
    __syncthreads();
    if (v){
      float a[4] = {B2[lane], B2[lane], B2[lane], B2[lane]};
      layerR<64,64,4,64>(W2, &hs[w][0][0], a, lane);
      #pragma unroll
      for (int r = 0; r < 4; ++r)
        sites2[((size_t)(4*G + r))*64 + lane] = fmaxf(a[r], 0.f);
    }
    __syncthreads();
  }
}

// ---------- kernel 3: bond kernel (fused bonds pre-MLP + gather + bond update) ----------
__global__ __launch_bounds__(256) void bond_kernel(
    const float* __restrict__ bonds,
    const float* __restrict__ wb1, const float* __restrict__ bb1,
    const float* __restrict__ wb2, const float* __restrict__ bb2,
    const float* __restrict__ w_bu1,
    const float* __restrict__ w_bu2, const float* __restrict__ b_bu2,
    const float* __restrict__ w_bu3, const float* __restrict__ b_bu3,
    const int* __restrict__ idx1, const int* __restrict__ idx2, const int* __restrict__ g2b,
    const float* __restrict__ sites2, const float* __restrict__ statec_bu,
    float* __restrict__ bonds_pool, int* __restrict__ cnt_pool, float* __restrict__ bonds_g,
    float* __restrict__ out_bonds)
{
  __shared__ float W1[4096], W2[4096], WA[4096], WB[4096], WC[4096];
  __shared__ float WU2[2048], WU3[2048];
  __shared__ float Bb1[64], Bb2[64], Bu2[32], Bu3[64];
  __shared__ alignas(16) float xs[4][4][64];   // bond input, later bonds2
  __shared__ alignas(16) float xp[4][4][64];   // sites2[i1]
  __shared__ alignas(16) float xq[4][4][64];   // sites2[i2]
  __shared__ alignas(16) float hs[4][4][64];
  __shared__ alignas(16) float h2[4][4][32];
  int tid = threadIdx.x;
  stage_w<4096>(W1, wb1,            tid, 256);
  stage_w<4096>(W2, wb2,            tid, 256);
  stage_w<4096>(WA, w_bu1,          tid, 256);
  stage_w<4096>(WB, w_bu1 + 64*64,  tid, 256);
  stage_w<4096>(WC, w_bu1 + 128*64, tid, 256);
  stage_w<2048>(WU2, w_bu2,         tid, 256);
  stage_w<2048>(WU3, w_bu3,         tid, 256);
  stage_b(Bb1, bb1, 64, tid); stage_b(Bb2, bb2, 64, tid);
  stage_b(Bu2, b_bu2, 32, tid); stage_b(Bu3, b_bu3, 64, tid);
  __syncthreads();
  int w = tid >> 6, lane = tid & 63;
  int ebase = blockIdx.x*256 + w*64;   // wave owns 64 CONTIGUOUS bonds (g2b sorted)
  float gacc = 0.f; int cur_g = -1;
  for (int it = 0; it < 16; ++it){
    int e0 = ebase + it*4;
    int i1a[4], gg[4];
    #pragma unroll
    for (int r = 0; r < 4; ++r){
      int e = e0 + r;
      int i1 = idx1[e], i2 = idx2[e];
      i1a[r] = i1; gg[r] = g2b[e];
      xs[w][r][lane] = bonds[(size_t)e*64 + lane];
      xp[w][r][lane] = sites2[(size_t)i1*64 + lane];
      xq[w][r][lane] = sites2[(size_t)i2*64 + lane];
    }
    __syncthreads();
    // bonds pre-MLP layer 1
    {
      float a[4] = {Bb1[lane], Bb1[lane], Bb1[lane], Bb1[lane]};
      layerR<64,64,4,64>(W1, &xs[w][0][0], a, lane);
      #pragma unroll
      for (int r = 0; r < 4; ++r) hs[w][r][lane] = fmaxf(a[r], 0.f);
    }
    __syncthreads();
    // bonds pre-MLP layer 2 -> bonds2 (residual), stash into xs
    float b2v[4];
    {
      float a[4] = {Bb2[lane], Bb2[lane], Bb2[lane], Bb2[lane]};
      layerR<64,64,4,64>(W2, &hs[w][0][0], a, lane);
      #pragma unroll
      for (int r = 0; r < 4; ++r) b2v[r] = fmaxf(a[r], 0.f);
    }
    __syncthreads();
    #pragma unroll
    for (int r = 0; r < 4; ++r) xs[w][r][lane] = b2v[r];
    __syncthreads();
    // bond-update fc1: A*s1 + B*s2 + C*bonds2 + (state slice incl. bias)
    {
      float a[4];
      #pragma unroll
      for (int r = 0; r < 4; ++r) a[r] = statec_bu[(size_t)gg[r]*64 + lane];
      layerR<64,64,4,64>(WA, &xp[w][0][0], a, lane);
      layerR<64,64,4,64>(WB, &xq[w][0][0], a, lane);
      layerR<64,64,4,64>(WC, &xs[w][0][0], a, lane);
      #pragma unroll
      for (int r = 0; r < 4; ++r) hs[w][r][lane] = fmaxf(a[r], 0.f);
    }
    __syncthreads();
    // bond-update fc2 (64 -> 32); all lanes compute j=lane&31, low lanes write
    {
      int j = lane & 31;
      float a[4] = {Bu2[j], Bu2[j], Bu2[j], Bu2[j]};
      layerR<64,32,4,64>(WU2, &hs[w][0][0], a, j);
      if (lane < 32){
        #pragma unroll
        for (int r = 0; r < 4; ++r) h2[w][r][lane] = fmaxf(a[r], 0.f);
      }
    }
    __syncthreads();
    // bond-update fc3 (32 -> 64) + epilogue
    {
      float a[4] = {Bu3[lane], Bu3[lane], Bu3[lane], Bu3[lane]};
      layerR<32,64,4,32>(WU3, &h2[w][0][0], a, lane);
      #pragma unroll
      for (int r = 0; r < 4; ++r){
        float bnew = fmaxf(a[r], 0.f);
        int e = e0 + r;
        out_bonds[(size_t)e*64 + lane] = bnew + b2v[r];
        atomicAdd(&bonds_pool[(size_t)i1a[r]*64 + lane], bnew);
        if (lane == 0) atomicAdd(&cnt_pool[i1a[r]], 1);
        if (gg[r] != cur_g){
          if (cur_g >= 0) atomicAdd(&bonds_g[(size_t)cur_g*64 + lane], gacc);
          cur_g = gg[r]; gacc = 0.f;
        }
        gacc += bnew;
      }
    }
    __syncthreads();
  }
  if (cur_g >= 0) atomicAdd(&bonds_g[(size_t)cur_g*64 + lane], gacc);
}

// ---------- kernel 4: site update (100000 rows) ----------
__global__ __launch_bounds__(256) void site_kernel(
    const float* __restrict__ sites2, const float* __restrict__ bonds_pool, const int* __restrict__ cnt_pool,
    const int* __restrict__ g2s, const float* __restrict__ statec_su,
    const float* __restrict__ w_su1, const float* __restrict__ w_su2, const float* __restrict__ b_su2,
    const float* __restrict__ w_su3, const float* __restrict__ b_su3,
    float* __restrict__ sites_g, float* __restrict__ out_sites)
{
  __shared__ float W1a[4096], W1b[4096], W2[2048], W3[2048];
  __shared__ float B2s[32], B3s[64];
  __shared__ alignas(16) float xp[4][4][64];
  __shared__ alignas(16) float xq[4][4][64];
  __shared__ alignas(16) float hs[4][4][64];
  __shared__ alignas(16) float h2[4][4][32];
  int tid = threadIdx.x;
  stage_w<4096>(W1a, w_su1,         tid, 256);
  stage_w<4096>(W1b, w_su1 + 64*64, tid, 256);
  stage_w<2048>(W2,  w_su2,         tid, 256);
  stage_w<2048>(W3,  w_su3,         tid, 256);
  stage_b(B2s, b_su2, 32, tid); stage_b(B3s, b_su3, 64, tid);
  __syncthreads();
  int w = tid >> 6, lane = tid & 63;
  int sbase = blockIdx.x*256 + w*64;   // contiguous sites per wave (g2s sorted)
  float gacc = 0.f; int cur_g = -1;
  for (int it = 0; it < 16; ++it){
    int s0 = sbase + it*4;
    int gg[4]; float s2v[4];
    #pragma unroll
    for (int r = 0; r < 4; ++r){
      int s = s0 + r;
      bool v = s < N_SITES;
      gg[r] = v ? g2s[s] : 0;
      float inv = v ? (1.f / fmaxf((float)cnt_pool[s], 1.f)) : 0.f;
      xp[w][r][lane] = v ? bonds_pool[(size_t)s*64 + lane] * inv : 0.f;
      s2v[r] = v ? sites2[(size_t)s*64 + lane] : 0.f;
      xq[w][r][lane] = s2v[r];
    }
    __syncthreads();
    {
      float a[4];
      #pragma unroll
      for (int r = 0; r < 4; ++r) a[r] = statec_su[(size_t)gg[r]*64 + lane];
      layerR<64,64,4,64>(W1a, &xp[w][0][0], a, lane);
      layerR<64,64,4,64>(W1b, &xq[w][0][0], a, lane);
      #pragma unroll
      for (int r = 0; r < 4; ++r) hs[w][r][lane] = fmaxf(a[r], 0.f);
    }
    __syncthreads();
    {
      int j = lane & 31;
      float a[4] = {B2s[j], B2s[j], B2s[j], B2s[j]};
      layerR<64,32,4,64>(W2, &hs[w][0][0], a, j);
      if (lane < 32){
        #pragma unroll
        for (int r = 0; r < 4; ++r) h2[w][r][lane] = fmaxf(a[r], 0.f);
      }
    }
    __syncthreads();
    {
      float a[4] = {B3s[lane], B3s[lane], B3s[lane], B3s[lane]};
      layerR<32,64,4,32>(W3, &h2[w][0][0], a, lane);
      #pragma unroll
      for (int r = 0; r < 4; ++r){
        int s = s0 + r;
        if (s < N_SITES){
          float snew = fmaxf(a[r], 0.f);
          out_sites[(size_t)s*64 + lane] = snew + s2v[r];
          if (gg[r] != cur_g){
            if (cur_g >= 0) atomicAdd(&sites_g[(size_t)cur_g*64 + lane], gacc);
            cur_g = gg[r]; gacc = 0.f;
          }
          gacc += snew;
        }
      }
    }
    __syncthreads();
  }
  if (cur_g >= 0) atomicAdd(&sites_g[(size_t)cur_g*64 + lane], gacc);
}

// ---------- kernel 5: state update (1000 graphs, one wave each) ----------
__global__ __launch_bounds__(64) void state_kernel(
    const float* __restrict__ states2, const float* __restrict__ bonds_g, const float* __restrict__ sites_g,
    const int* __restrict__ g2b, const int* __restrict__ g2s,
    const float* __restrict__ w_stu1, const float* __restrict__ w_stu2, const float* __restrict__ b_stu2,
    const float* __restrict__ w_stu3, const float* __restrict__ b_stu3,
    const float* __restrict__ statec_stu, float* __restrict__ out_states)
{
  __shared__ float W1a[4096], W1b[4096], W2[2048], W3[2048];
  __shared__ float B2s[32], B3s[64];
  __shared__ alignas(16) float xb[64], xsit[64], hsx[64], h2x[32];
  __shared__ int cnts[2];
  int lane = threadIdx.x; int g = blockIdx.x;
  stage_w<4096>(W1a, w_stu1,         lane, 64);
  stage_w<4096>(W1b, w_stu1 + 64*64, lane, 64);
  stage_w<2048>(W2,  w_stu2,         lane, 64);
  stage_w<2048>(W3,  w_stu3,         lane, 64);
  stage_b(B2s, b_stu2, 32, lane); stage_b(B3s, b_stu3, 64, lane);
  if (lane == 0){
    cnts[0] = lbound(g2b, N_BONDS, g+1) - lbound(g2b, N_BONDS, g);
    cnts[1] = lbound(g2s, N_SITES, g+1) - lbound(g2s, N_SITES, g);
  }
  __syncthreads();
  float invb = 1.f / fmaxf((float)cnts[0], 1.f);
  float invs = 1.f / fmaxf((float)cnts[1], 1.f);
  xb[lane]   = bonds_g[(size_t)g*64 + lane] * invb;
  xsit[lane] = sites_g[(size_t)g*64 + lane] * invs;
  __syncthreads();
  {
    float a = statec_stu[(size_t)g*64 + lane];
    layerR<64,64,1,64>(W1a, xb,   &a, lane);
    layerR<64,64,1,64>(W1b, xsit, &a, lane);
    hsx[lane] = fmaxf(a, 0.f);
  }
  __syncthreads();
  {
    int j = lane & 31;
    float a = B2s[j];
    layerR<64,32,1,64>(W2, hsx, &a, j);
    if (lane < 32) h2x[lane] = fmaxf(a, 0.f);
  }
  __syncthreads();
  {
    float a = B3s[lane];
    layerR<32,64,1,32>(W3, h2x, &a, lane);
    out_states[(size_t)g*64 + lane] = fmaxf(a, 0.f) + states2[(size_t)g*64 + lane];
  }
}

// ---------- launch ----------
extern "C" void kernel_launch(void* const* d_in, const int* in_sizes, int n_in,
                              void* d_out, int out_size, void* d_ws, size_t ws_size,
                              hipStream_t stream)
{
  const float* sites   = (const float*)d_in[0];
  const float* bonds   = (const float*)d_in[1];
  const float* states  = (const float*)d_in[2];
  const float* w_sites1 = (const float*)d_in[3];  const float* b_sites1 = (const float*)d_in[4];
  const float* w_sites2 = (const float*)d_in[5];  const float* b_sites2 = (const float*)d_in[6];
  const float* w_bonds1 = (const float*)d_in[7];  const float* b_bonds1 = (const float*)d_in[8];
  const float* w_bonds2 = (const float*)d_in[9];  const float* b_bonds2 = (const float*)d_in[10];
  const float* w_states1= (const float*)d_in[11]; const float* b_states1= (const float*)d_in[12];
  const float* w_states2= (const float*)d_in[13]; const float* b_states2= (const float*)d_in[14];
  const float* w_bu1 = (const float*)d_in[15]; const float* b_bu1 = (const float*)d_in[16];
  const float* w_bu2 = (const float*)d_in[17]; const float* b_bu2 = (const float*)d_in[18];
  const float* w_bu3 = (const float*)d_in[19]; const float* b_bu3 = (const float*)d_in[20];
  const float* w_su1 = (const float*)d_in[21]; const float* b_su1 = (const float*)d_in[22];
  const float* w_su2 = (const float*)d_in[23]; const float* b_su2 = (const float*)d_in[24];
  const float* w_su3 = (const float*)d_in[25]; const float* b_su3 = (const float*)d_in[26];
  const float* w_stu1= (const float*)d_in[27]; const float* b_stu1= (const float*)d_in[28];
  const float* w_stu2= (const float*)d_in[29]; const float* b_stu2= (const float*)d_in[30];
  const float* w_stu3= (const float*)d_in[31]; const float* b_stu3= (const float*)d_in[32];
  const int* idx1 = (const int*)d_in[33];
  const int* idx2 = (const int*)d_in[34];
  const int* g2s  = (const int*)d_in[35];
  const int* g2b  = (const int*)d_in[36];

  // d_ws usage: ~27.6 MB
  float* p = (float*)d_ws;
  float* bonds_pool = p;        p += (size_t)N_SITES*64;     // zeroed
  float* bonds_g    = p;        p += (size_t)N_GRAPHS*64;    // zeroed
  float* sites_g    = p;        p += (size_t)N_GRAPHS*64;    // zeroed
  int*   cnt_pool   = (int*)p;  p += N_SITES;                // zeroed
  float* states2    = p;        p += (size_t)N_GRAPHS*64;
  float* statec_bu  = p;        p += (size_t)N_GRAPHS*64;
  float* statec_su  = p;        p += (size_t)N_GRAPHS*64;
  float* statec_stu = p;        p += (size_t)N_GRAPHS*64;

  size_t zero_bytes = ((size_t)N_SITES*64 + 2*(size_t)N_GRAPHS*64 + (size_t)N_SITES) * 4;
  hipMemsetAsync(d_ws, 0, zero_bytes, stream);

  float* out_sites  = (float*)d_out;
  float* out_bonds  = out_sites + (size_t)N_SITES*64;
  float* out_states = out_bonds + (size_t)N_BONDS*64;
  float* sites2     = out_sites;   // fp32 sites2 staged in the sites output
                                   // region: written by sites_pre, gathered by
                                   // bond_kernel, read-then-overwritten in
                                   // place by site_kernel (each element only
                                   // by its owning thread).

  hipLaunchKernelGGL(prep_small_kernel, dim3(250), dim3(256), 0, stream,
      states, w_states1, b_states1, w_states2, b_states2,
      w_bu1, b_bu1, w_su1, b_su1, w_stu1, b_stu1,
      states2, statec_bu, statec_su, statec_stu);

  hipLaunchKernelGGL(sites_pre_kernel, dim3(1024), dim3(256), 0, stream,
      sites, w_sites1, b_sites1, w_sites2, b_sites2, sites2);

  hipLaunchKernelGGL(bond_kernel, dim3(3125), dim3(256), 0, stream,
      bonds, w_bonds1, b_bonds1, w_bonds2, b_bonds2,
      w_bu1, w_bu2, b_bu2, w_bu3, b_bu3,
      idx1, idx2, g2b, sites2, statec_bu,
      bonds_pool, cnt_pool, bonds_g, out_bonds);

  hipLaunchKernelGGL(site_kernel, dim3(391), dim3(256), 0, stream,
      sites2, bonds_pool, cnt_pool, g2s, statec_su,
      w_su1, w_su2, b_su2, w_su3, b_su3,
      sites_g, out_sites);

  hipLaunchKernelGGL(state_kernel, dim3(1000), dim3(64), 0, stream,
      states2, bonds_g, sites_g, g2b, g2s,
      w_stu1, w_stu2, b_stu2, w_stu3, b_stu3,
      statec_stu, out_states);
}